// Round 8
// baseline (125.674 us; speedup 1.0000x reference)
//
#include <hip/hip_runtime.h>

typedef __attribute__((ext_vector_type(8))) _Float16 half8;
typedef __attribute__((ext_vector_type(4))) float f32x4;
typedef __attribute__((ext_vector_type(4))) unsigned int uint4v;

namespace {
constexpr int kB = 2048;
constexpr int kF = 64;
constexpr int kC = 10;
constexpr int kS = 5;
constexpr int kG = kC + kS;          // 15 groups
constexpr int kH1 = 32;
constexpr int kH2 = 16;
constexpr float kWCat = 0.7f / kC;
constexpr float kWSub = 0.3f / kS;
constexpr int kThreads = 256;        // 4 waves
constexpr int kRowsPerBlock = 128;   // 4 waves x 2 tiles x 16 rows
constexpr int kChunks = kB / kRowsPerBlock;   // 16 -> grid = 64*16 = 1024
// ws: pp[2048][64] partials (512 KB), then 16 int tickets.
constexpr size_t kTicketOffB = (size_t)kB * kF * sizeof(float);
}

// Fused kernel: each block computes one (f, 128-row chunk)'s partials into
// pp[row][f]; the last block of each chunk (device-scope atomic ticket)
// reduces the chunk's rows over all 64 f and writes out. No reduce node.
__global__ __launch_bounds__(kThreads, 4) void nam_fused(
    const float* __restrict__ x,
    const float* __restrict__ cbias, const float* __restrict__ sbias,
    const float* __restrict__ cW1, const float* __restrict__ cB1,
    const float* __restrict__ cW2, const float* __restrict__ cB2,
    const float* __restrict__ cW3, const float* __restrict__ cB3,
    const float* __restrict__ sW1, const float* __restrict__ sB1,
    const float* __restrict__ sW2, const float* __restrict__ sB2,
    const float* __restrict__ sW3, const float* __restrict__ sB3,
    float* __restrict__ pp, int* __restrict__ tickets,
    float* __restrict__ out) {
    const int f     = blockIdx.x & (kF - 1);
    const int chunk = blockIdx.x >> 6;
    const int tid   = threadIdx.x;

    // LDS staging of all 15 groups' weights for this f (~25 KB).
    __shared__ float    lW1B1[kG][4][16];   // [g][kg][0..7 w1, 8..15 b1]
    __shared__ _Float16 lW2T[kG][16][40];   // [g][n][k] f16, padded to 40
    __shared__ float2   lWC[kG][16];        // {W3*wgt, B2}
    __shared__ float    lB3[kG];            // wgt * b3
    __shared__ int      lTicket;

    for (int i = tid; i < kG * 64; i += kThreads) {
        const int g = i >> 6, r = i & 63;
        const int kg = r >> 4, e = r & 15;
        const int base = ((g < kC) ? (g * kF + f) : ((g - kC) * kF + f)) * kH1
                         + kg * 8 + (e & 7);
        const float* src = (e < 8) ? ((g < kC) ? cW1 : sW1)
                                   : ((g < kC) ? cB1 : sB1);
        lW1B1[g][kg][e] = src[base];
    }
    for (int i = tid; i < kG * 512; i += kThreads) {
        const int g = i >> 9, e = i & 511;
        const int k = e >> 4, n = e & 15;
        const float* src = (g < kC) ? (cW2 + (size_t)(g * kF + f) * 512)
                                    : (sW2 + (size_t)((g - kC) * kF + f) * 512);
        lW2T[g][n][k] = (_Float16)src[e];
    }
    for (int i = tid; i < kG * kH2; i += kThreads) {
        const int g = i >> 4, nn = i & 15;
        const int base = ((g < kC) ? (g * kF + f) : ((g - kC) * kF + f)) * kH2 + nn;
        float2 v;
        v.x = ((g < kC) ? cW3 : sW3)[base] * ((g < kC) ? kWCat : kWSub);
        v.y = ((g < kC) ? cB2 : sB2)[base];
        lWC[g][nn] = v;
    }
    if (tid < kG) {
        const int g = tid;
        lB3[g] = (g < kC) ? kWCat * cB3[g * kF + f]
                          : kWSub * sB3[(g - kC) * kF + f];
    }
    __syncthreads();

    const int wave = tid >> 6;
    const int lane = tid & 63;
    const int n  = lane & 15;
    const int kg = lane >> 4;
    const int rowbase = chunk * kRowsPerBlock + wave * 32;

    const float xv0 = x[(size_t)(rowbase + n) * kF + f];
    const float xv1 = x[(size_t)(rowbase + 16 + n) * kF + f];

    float outp[2][4] = {{0.f, 0.f, 0.f, 0.f}, {0.f, 0.f, 0.f, 0.f}};
    float bcon = 0.f;

    #pragma unroll 2
    for (int g = 0; g < kG; ++g) {
        const f32x4 w1a = *(const f32x4*)&lW1B1[g][kg][0];
        const f32x4 w1b = *(const f32x4*)&lW1B1[g][kg][4];
        const f32x4 b1a = *(const f32x4*)&lW1B1[g][kg][8];
        const f32x4 b1b = *(const f32x4*)&lW1B1[g][kg][12];
        const half8 bw  = *(const half8*)&lW2T[g][n][kg * 8];
        const float2 wc = lWC[g][n];
        bcon += lB3[g];

        #pragma unroll
        for (int t = 0; t < 2; ++t) {
            const float xv = t ? xv1 : xv0;
            float h0 = fmaxf(fmaf(xv, w1a.x, b1a.x), 0.f);
            float h1 = fmaxf(fmaf(xv, w1a.y, b1a.y), 0.f);
            float h2 = fmaxf(fmaf(xv, w1a.z, b1a.z), 0.f);
            float h3 = fmaxf(fmaf(xv, w1a.w, b1a.w), 0.f);
            float h4 = fmaxf(fmaf(xv, w1b.x, b1b.x), 0.f);
            float h5 = fmaxf(fmaf(xv, w1b.y, b1b.y), 0.f);
            float h6 = fmaxf(fmaf(xv, w1b.z, b1b.z), 0.f);
            float h7 = fmaxf(fmaf(xv, w1b.w, b1b.w), 0.f);
            uint4v uu;
            uu.x = __builtin_bit_cast(unsigned, __builtin_amdgcn_cvt_pkrtz(h0, h1));
            uu.y = __builtin_bit_cast(unsigned, __builtin_amdgcn_cvt_pkrtz(h2, h3));
            uu.z = __builtin_bit_cast(unsigned, __builtin_amdgcn_cvt_pkrtz(h4, h5));
            uu.w = __builtin_bit_cast(unsigned, __builtin_amdgcn_cvt_pkrtz(h6, h7));
            const half8 aw = __builtin_bit_cast(half8, uu);
            f32x4 c = { wc.y, wc.y, wc.y, wc.y };
            c = __builtin_amdgcn_mfma_f32_16x16x32_f16(aw, bw, c, 0, 0, 0);
            // C/D: col = lane&15, row = kg*4 + r
            #pragma unroll
            for (int r = 0; r < 4; ++r)
                outp[t][r] = fmaf(fmaxf(c[r], 0.f), wc.x, outp[t][r]);
        }
    }

    // Reduce over the 16 h2-columns; n==0 lanes store partials to pp[row][f].
    #pragma unroll
    for (int t = 0; t < 2; ++t)
        #pragma unroll
        for (int r = 0; r < 4; ++r) {
            float v = outp[t][r];
            v += __shfl_xor(v, 1);
            v += __shfl_xor(v, 2);
            v += __shfl_xor(v, 4);
            v += __shfl_xor(v, 8);
            if (n == 0)
                pp[(size_t)(rowbase + t * 16 + kg * 4 + r) * kF + f] = v + bcon;
        }

    // Last block of this chunk (64 writer blocks) reduces and writes out.
    __threadfence();                       // release my pp stores (device scope)
    if (tid == 0) lTicket = atomicAdd(&tickets[chunk], 1);
    __syncthreads();
    if (lTicket != kF - 1) return;
    __threadfence();                       // acquire all writers' pp stores

    float bs = 0.f;
    #pragma unroll
    for (int i = 0; i < kC; ++i) bs = fmaf(cbias[i], kWCat, bs);
    #pragma unroll
    for (int i = 0; i < kS; ++i) bs = fmaf(sbias[i], kWSub, bs);

    if (tid < kRowsPerBlock) {
        const int row = chunk * kRowsPerBlock + tid;
        const f32x4* pr = (const f32x4*)(pp + (size_t)row * kF);
        f32x4 s4 = pr[0];
        #pragma unroll
        for (int j = 1; j < kF / 4; ++j) s4 += pr[j];
        out[row] = s4.x + s4.y + s4.z + s4.w + bs;
    }
}

extern "C" void kernel_launch(void* const* d_in, const int* in_sizes, int n_in,
                              void* d_out, int out_size, void* d_ws, size_t ws_size,
                              hipStream_t stream) {
    const float* x     = (const float*)d_in[0];
    const float* cW1   = (const float*)d_in[1];
    const float* cB1   = (const float*)d_in[2];
    const float* cW2   = (const float*)d_in[3];
    const float* cB2   = (const float*)d_in[4];
    const float* cW3   = (const float*)d_in[5];
    const float* cB3   = (const float*)d_in[6];
    const float* cbias = (const float*)d_in[7];
    const float* sW1   = (const float*)d_in[8];
    const float* sB1   = (const float*)d_in[9];
    const float* sW2   = (const float*)d_in[10];
    const float* sB2   = (const float*)d_in[11];
    const float* sW3   = (const float*)d_in[12];
    const float* sB3   = (const float*)d_in[13];
    const float* sbias = (const float*)d_in[14];
    float* out = (float*)d_out;
    float* pp  = (float*)d_ws;                                  // 512 KB
    int* tickets = (int*)((char*)d_ws + kTicketOffB);           // 16 ints
    (void)ws_size; (void)n_in; (void)in_sizes; (void)out_size;

    hipMemsetAsync(tickets, 0, kChunks * sizeof(int), stream);
    nam_fused<<<kF * kChunks, kThreads, 0, stream>>>(
        x, cbias, sbias, cW1, cB1, cW2, cB2, cW3, cB3,
        sW1, sB1, sW2, sB2, sW3, sB3, pp, tickets, out);
}

// Round 9
// 27.732 us; speedup vs baseline: 4.5317x; 4.5317x over previous
//
#include <hip/hip_runtime.h>

typedef __attribute__((ext_vector_type(8))) _Float16 half8;
typedef __attribute__((ext_vector_type(4))) float f32x4;
typedef __attribute__((ext_vector_type(4))) unsigned int uint4v;

namespace {
constexpr int kB = 2048;
constexpr int kF = 64;
constexpr int kC = 10;
constexpr int kS = 5;
constexpr int kG = kC + kS;          // 15 groups
constexpr int kH1 = 32;
constexpr int kH2 = 16;
constexpr float kWCat = 0.7f / kC;
constexpr float kWSub = 0.3f / kS;
constexpr int kThreads = 256;        // 4 waves
constexpr int kRowsPerBlock = 256;   // 4 waves x 4 tiles x 16 rows
constexpr int kChunks = kB / kRowsPerBlock;   // 8 -> grid = 64*8 = 512

// Packed record: 384 floats per (f,g), f-major ([f][g][384]):
//   [0..63]   W1B1: [kg][0..7]=w1[kg*8+j], [kg][8..15]=b1[kg*8+j]
//   [64..319] B-fragment: lane l -> half8 at float offset 64+4*l
//   [320..351] {W3[n]*wgt, B2[n]} pairs at 320+2*n
//   [352]     wgt*b3      [353..383] pad
constexpr int kRecF = 384;
constexpr int kFStageF = kG * kRecF;               // 5760 floats per f
// ws layout (floats): pack[960*384] | xT[64*2048] | pp[64*2048]
constexpr size_t kXTOff = (size_t)kG * kF * kRecF;         // 368640
constexpr size_t kPPOff = kXTOff + (size_t)kF * kB;        // +131072
}

// Node 1: LDS-tiled transpose x (B,F) -> xT (F,B). 32 blocks.
__global__ __launch_bounds__(kThreads) void transpose_kernel(
    const float* __restrict__ x, float* __restrict__ xT) {
    __shared__ float tile[64][65];
    const int b0 = blockIdx.x * 64;
    const int c = threadIdx.x & 63, r4 = threadIdx.x >> 6;
    #pragma unroll
    for (int j = 0; j < 16; ++j) {
        const int r = j * 4 + r4;
        tile[r][c] = x[(size_t)(b0 + r) * kF + c];   // coalesced read
    }
    __syncthreads();
    #pragma unroll
    for (int j = 0; j < 16; ++j) {
        const int fr = j * 4 + r4;
        xT[(size_t)fr * kB + b0 + c] = tile[c][fr];  // coalesced write
    }
}

// Node 2: pack weights into fragment-ready records. One wave per (g,f);
// every weight byte is read from HBM exactly once, coalesced.
__global__ __launch_bounds__(64) void pack_kernel(
    const float* __restrict__ cW1, const float* __restrict__ cB1,
    const float* __restrict__ cW2, const float* __restrict__ cB2,
    const float* __restrict__ cW3, const float* __restrict__ cB3,
    const float* __restrict__ sW1, const float* __restrict__ sB1,
    const float* __restrict__ sW2, const float* __restrict__ sB2,
    const float* __restrict__ sW3, const float* __restrict__ sB3,
    float* __restrict__ wsPack) {
    const int g = blockIdx.x >> 6, f = blockIdx.x & (kF - 1);
    const int l = threadIdx.x;
    const float *W1, *B1, *W2, *B2, *W3, *B3; float wgt; int base;
    if (g < kC) {
        base = g * kF + f;
        W1 = cW1; B1 = cB1; W2 = cW2; B2 = cB2; W3 = cW3; B3 = cB3; wgt = kWCat;
    } else {
        base = (g - kC) * kF + f;
        W1 = sW1; B1 = sB1; W2 = sW2; B2 = sB2; W3 = sW3; B3 = sB3; wgt = kWSub;
    }
    float* rec = wsPack + ((size_t)f * kG + g) * kRecF;

    // B-fragment: lane l -> fp16(W2[k=(l>>4)*8+j][n=l&15]), j=0..7.
    const int n = l & 15, kg = l >> 4;
    const float* w2p = W2 + (size_t)base * (kH1 * kH2) + (kg * 8) * kH2 + n;
    half8 bw;
    #pragma unroll
    for (int j = 0; j < 8; ++j) bw[j] = (_Float16)w2p[j * kH2];
    *(half8*)(rec + 64 + 4 * l) = bw;

    if (l < kH1) {
        rec[(l >> 3) * 16 + (l & 7)]     = W1[(size_t)base * kH1 + l];
        rec[(l >> 3) * 16 + 8 + (l & 7)] = B1[(size_t)base * kH1 + l];
    }
    if (l < kH2) {
        float2 v;
        v.x = W3[(size_t)base * kH2 + l] * wgt;
        v.y = B2[(size_t)base * kH2 + l];
        *(float2*)(rec + 320 + 2 * l) = v;
    }
    if (l == 0) rec[352] = wgt * B3[base];
}

// Node 3: one block per (f, 256-row chunk): 512 blocks. Stage this f's 15
// packed records (22.5 KB) with 6 coalesced float4 rounds, then the f16-MFMA
// group loop over 4 tiles/wave. Plain stores of per-f partials to pp[f][row].
__global__ __launch_bounds__(kThreads, 4) void nam_packed(
    const float* __restrict__ xT, const float* __restrict__ wsPack,
    float* __restrict__ pp) {
    const int f     = blockIdx.x & (kF - 1);
    const int chunk = blockIdx.x >> 6;
    const int tid   = threadIdx.x;

    __shared__ float lds[kFStageF];   // 23040 B
    const float4* src = (const float4*)(wsPack + (size_t)f * kFStageF);
    #pragma unroll
    for (int r = 0; r < 6; ++r) {
        const int idx = tid + r * kThreads;
        if (idx < kFStageF / 4) ((float4*)lds)[idx] = src[idx];
    }
    __syncthreads();

    const int wave = tid >> 6;
    const int lane = tid & 63;
    const int n  = lane & 15;
    const int kg = lane >> 4;
    const int rowbase = chunk * kRowsPerBlock + wave * 64;

    float xv[4];
    #pragma unroll
    for (int t = 0; t < 4; ++t) xv[t] = xT[(size_t)f * kB + rowbase + t * 16 + n];

    float outp[4][4];
    #pragma unroll
    for (int t = 0; t < 4; ++t)
        #pragma unroll
        for (int r = 0; r < 4; ++r) outp[t][r] = 0.f;
    float bcon = 0.f;

    #pragma unroll 3
    for (int g = 0; g < kG; ++g) {
        const float* rec = lds + g * kRecF;
        const f32x4 w1a = *(const f32x4*)(rec + kg * 16);
        const f32x4 w1b = *(const f32x4*)(rec + kg * 16 + 4);
        const f32x4 b1a = *(const f32x4*)(rec + kg * 16 + 8);
        const f32x4 b1b = *(const f32x4*)(rec + kg * 16 + 12);
        const half8 bw  = *(const half8*)(rec + 64 + 4 * lane);
        const float2 wc = *(const float2*)(rec + 320 + 2 * n);
        bcon += rec[352];

        #pragma unroll
        for (int t = 0; t < 4; ++t) {
            const float v = xv[t];
            float h0 = fmaxf(fmaf(v, w1a.x, b1a.x), 0.f);
            float h1 = fmaxf(fmaf(v, w1a.y, b1a.y), 0.f);
            float h2 = fmaxf(fmaf(v, w1a.z, b1a.z), 0.f);
            float h3 = fmaxf(fmaf(v, w1a.w, b1a.w), 0.f);
            float h4 = fmaxf(fmaf(v, w1b.x, b1b.x), 0.f);
            float h5 = fmaxf(fmaf(v, w1b.y, b1b.y), 0.f);
            float h6 = fmaxf(fmaf(v, w1b.z, b1b.z), 0.f);
            float h7 = fmaxf(fmaf(v, w1b.w, b1b.w), 0.f);
            uint4v uu;
            uu.x = __builtin_bit_cast(unsigned, __builtin_amdgcn_cvt_pkrtz(h0, h1));
            uu.y = __builtin_bit_cast(unsigned, __builtin_amdgcn_cvt_pkrtz(h2, h3));
            uu.z = __builtin_bit_cast(unsigned, __builtin_amdgcn_cvt_pkrtz(h4, h5));
            uu.w = __builtin_bit_cast(unsigned, __builtin_amdgcn_cvt_pkrtz(h6, h7));
            const half8 aw = __builtin_bit_cast(half8, uu);
            f32x4 c = { wc.y, wc.y, wc.y, wc.y };
            c = __builtin_amdgcn_mfma_f32_16x16x32_f16(aw, bw, c, 0, 0, 0);
            // C/D: col = lane&15, row = kg*4 + r
            #pragma unroll
            for (int r = 0; r < 4; ++r)
                outp[t][r] = fmaf(fmaxf(c[r], 0.f), wc.x, outp[t][r]);
        }
    }

    #pragma unroll
    for (int t = 0; t < 4; ++t)
        #pragma unroll
        for (int r = 0; r < 4; ++r) {
            float v = outp[t][r];
            v += __shfl_xor(v, 1);
            v += __shfl_xor(v, 2);
            v += __shfl_xor(v, 4);
            v += __shfl_xor(v, 8);
            if (n == 0)
                pp[(size_t)f * kB + rowbase + t * 16 + kg * 4 + r] = v + bcon;
        }
}

// Node 4: out[b] = sum_f pp[f][b] + weighted group-bias constant.
__global__ __launch_bounds__(kThreads) void reduce_kernel(
    const float* __restrict__ pp,
    const float* __restrict__ cbias, const float* __restrict__ sbias,
    float* __restrict__ out) {
    const int b = blockIdx.x * kThreads + threadIdx.x;
    float s = 0.f;
    #pragma unroll 8
    for (int f = 0; f < kF; ++f) s += pp[(size_t)f * kB + b];   // coalesced per f
    float bs = 0.f;
    #pragma unroll
    for (int i = 0; i < kC; ++i) bs = fmaf(cbias[i], kWCat, bs);
    #pragma unroll
    for (int i = 0; i < kS; ++i) bs = fmaf(sbias[i], kWSub, bs);
    out[b] = s + bs;
}

extern "C" void kernel_launch(void* const* d_in, const int* in_sizes, int n_in,
                              void* d_out, int out_size, void* d_ws, size_t ws_size,
                              hipStream_t stream) {
    const float* x     = (const float*)d_in[0];
    const float* cW1   = (const float*)d_in[1];
    const float* cB1   = (const float*)d_in[2];
    const float* cW2   = (const float*)d_in[3];
    const float* cB2   = (const float*)d_in[4];
    const float* cW3   = (const float*)d_in[5];
    const float* cB3   = (const float*)d_in[6];
    const float* cbias = (const float*)d_in[7];
    const float* sW1   = (const float*)d_in[8];
    const float* sB1   = (const float*)d_in[9];
    const float* sW2   = (const float*)d_in[10];
    const float* sB2   = (const float*)d_in[11];
    const float* sW3   = (const float*)d_in[12];
    const float* sB3   = (const float*)d_in[13];
    const float* sbias = (const float*)d_in[14];
    float* out = (float*)d_out;

    float* wsPack = (float*)d_ws;
    float* xT = (float*)d_ws + kXTOff;
    float* pp = (float*)d_ws + kPPOff;
    (void)ws_size; (void)n_in; (void)in_sizes; (void)out_size;

    transpose_kernel<<<kB / 64, kThreads, 0, stream>>>(x, xT);
    pack_kernel<<<kG * kF, 64, 0, stream>>>(cW1, cB1, cW2, cB2, cW3, cB3,
                                            sW1, sB1, sW2, sB2, sW3, sB3, wsPack);
    nam_packed<<<kF * kChunks, kThreads, 0, stream>>>(xT, wsPack, pp);
    reduce_kernel<<<kB / kThreads, kThreads, 0, stream>>>(pp, cbias, sbias, out);
}

// Round 10
// 26.848 us; speedup vs baseline: 4.6809x; 1.0329x over previous
//
#include <hip/hip_runtime.h>

typedef __attribute__((ext_vector_type(8))) _Float16 half8;
typedef __attribute__((ext_vector_type(4))) float f32x4;
typedef __attribute__((ext_vector_type(4))) unsigned int uint4v;

namespace {
constexpr int kB = 2048;
constexpr int kF = 64;
constexpr int kC = 10;
constexpr int kS = 5;
constexpr int kG = kC + kS;          // 15 groups
constexpr int kH1 = 32;
constexpr int kH2 = 16;
constexpr float kWCat = 0.7f / kC;
constexpr float kWSub = 0.3f / kS;
constexpr int kThreads = 256;        // 4 waves
constexpr int kRowsPerBlock = 256;   // 4 waves x 4 tiles x 16 rows
constexpr int kChunks = kB / kRowsPerBlock;   // 8 -> grid = 64*8 = 512

// Packed record: 384 floats per (f,g), f-major ([f][g][384]):
//   [0..63]   W1B1: [kg][0..7]=w1[kg*8+j], [kg][8..15]=b1[kg*8+j]
//   [64..319] B-fragment: lane l -> half8 at float offset 64+4*l
//   [320..351] {W3[n]*wgt, B2[n]} pairs at 320+2*n
//   [352]     wgt*b3      [353..383] pad
constexpr int kRecF = 384;
constexpr int kFStageF = kG * kRecF;               // 5760 floats per f
}

// Node 1: pack weights into fragment-ready records (one wave per (g,f);
// every weight byte read from HBM exactly once, coalesced). Blocks 0..31
// additionally zero out[] (nam accumulates into it atomically afterwards).
__global__ __launch_bounds__(64) void pack_kernel(
    const float* __restrict__ cW1, const float* __restrict__ cB1,
    const float* __restrict__ cW2, const float* __restrict__ cB2,
    const float* __restrict__ cW3, const float* __restrict__ cB3,
    const float* __restrict__ sW1, const float* __restrict__ sB1,
    const float* __restrict__ sW2, const float* __restrict__ sB2,
    const float* __restrict__ sW3, const float* __restrict__ sB3,
    float* __restrict__ wsPack, float* __restrict__ out) {
    const int g = blockIdx.x >> 6, f = blockIdx.x & (kF - 1);
    const int l = threadIdx.x;
    if (blockIdx.x < kB / 64) out[blockIdx.x * 64 + l] = 0.f;

    const float *W1, *B1, *W2, *B2, *W3, *B3; float wgt; int base;
    if (g < kC) {
        base = g * kF + f;
        W1 = cW1; B1 = cB1; W2 = cW2; B2 = cB2; W3 = cW3; B3 = cB3; wgt = kWCat;
    } else {
        base = (g - kC) * kF + f;
        W1 = sW1; B1 = sB1; W2 = sW2; B2 = sB2; W3 = sW3; B3 = sB3; wgt = kWSub;
    }
    float* rec = wsPack + ((size_t)f * kG + g) * kRecF;

    // B-fragment: lane l -> fp16(W2[k=(l>>4)*8+j][n=l&15]), j=0..7.
    const int n = l & 15, kg = l >> 4;
    const float* w2p = W2 + (size_t)base * (kH1 * kH2) + (kg * 8) * kH2 + n;
    half8 bw;
    #pragma unroll
    for (int j = 0; j < 8; ++j) bw[j] = (_Float16)w2p[j * kH2];
    *(half8*)(rec + 64 + 4 * l) = bw;

    if (l < kH1) {
        rec[(l >> 3) * 16 + (l & 7)]     = W1[(size_t)base * kH1 + l];
        rec[(l >> 3) * 16 + 8 + (l & 7)] = B1[(size_t)base * kH1 + l];
    }
    if (l < kH2) {
        float2 v;
        v.x = W3[(size_t)base * kH2 + l] * wgt;
        v.y = B2[(size_t)base * kH2 + l];
        *(float2*)(rec + 320 + 2 * l) = v;
    }
    if (l == 0) rec[352] = wgt * B3[base];
}

// Node 2: one block per (f, 256-row chunk): 512 blocks. Stage this f's 15
// packed records (22.5 KB) with coalesced float4 rounds, run the f16-MFMA
// group loop (4 tiles/wave), then atomicAdd per-row contributions into out.
__global__ __launch_bounds__(kThreads, 4) void nam_packed(
    const float* __restrict__ x, const float* __restrict__ wsPack,
    const float* __restrict__ cbias, const float* __restrict__ sbias,
    float* __restrict__ out) {
    const int f     = blockIdx.x & (kF - 1);
    const int chunk = blockIdx.x >> 6;
    const int tid   = threadIdx.x;

    __shared__ float lds[kFStageF];   // 23040 B
    const float4* src = (const float4*)(wsPack + (size_t)f * kFStageF);
    #pragma unroll
    for (int r = 0; r < 6; ++r) {
        const int idx = tid + r * kThreads;
        if (idx < kFStageF / 4) ((float4*)lds)[idx] = src[idx];
    }
    __syncthreads();

    const int wave = tid >> 6;
    const int lane = tid & 63;
    const int n  = lane & 15;
    const int kg = lane >> 4;
    const int rowbase = chunk * kRowsPerBlock + wave * 64;

    // x[row][f]: each 64B line holds all 64 f -> L2-broadcast across blocks.
    float xv[4];
    #pragma unroll
    for (int t = 0; t < 4; ++t)
        xv[t] = x[(size_t)(rowbase + t * 16 + n) * kF + f];

    float outp[4][4];
    #pragma unroll
    for (int t = 0; t < 4; ++t)
        #pragma unroll
        for (int r = 0; r < 4; ++r) outp[t][r] = 0.f;
    float bcon = 0.f;

    #pragma unroll 3
    for (int g = 0; g < kG; ++g) {
        const float* rec = lds + g * kRecF;
        const f32x4 w1a = *(const f32x4*)(rec + kg * 16);
        const f32x4 w1b = *(const f32x4*)(rec + kg * 16 + 4);
        const f32x4 b1a = *(const f32x4*)(rec + kg * 16 + 8);
        const f32x4 b1b = *(const f32x4*)(rec + kg * 16 + 12);
        const half8 bw  = *(const half8*)(rec + 64 + 4 * lane);
        const float2 wc = *(const float2*)(rec + 320 + 2 * n);
        bcon += rec[352];

        #pragma unroll
        for (int t = 0; t < 4; ++t) {
            const float v = xv[t];
            float h0 = fmaxf(fmaf(v, w1a.x, b1a.x), 0.f);
            float h1 = fmaxf(fmaf(v, w1a.y, b1a.y), 0.f);
            float h2 = fmaxf(fmaf(v, w1a.z, b1a.z), 0.f);
            float h3 = fmaxf(fmaf(v, w1a.w, b1a.w), 0.f);
            float h4 = fmaxf(fmaf(v, w1b.x, b1b.x), 0.f);
            float h5 = fmaxf(fmaf(v, w1b.y, b1b.y), 0.f);
            float h6 = fmaxf(fmaf(v, w1b.z, b1b.z), 0.f);
            float h7 = fmaxf(fmaf(v, w1b.w, b1b.w), 0.f);
            uint4v uu;
            uu.x = __builtin_bit_cast(unsigned, __builtin_amdgcn_cvt_pkrtz(h0, h1));
            uu.y = __builtin_bit_cast(unsigned, __builtin_amdgcn_cvt_pkrtz(h2, h3));
            uu.z = __builtin_bit_cast(unsigned, __builtin_amdgcn_cvt_pkrtz(h4, h5));
            uu.w = __builtin_bit_cast(unsigned, __builtin_amdgcn_cvt_pkrtz(h6, h7));
            const half8 aw = __builtin_bit_cast(half8, uu);
            f32x4 c = { wc.y, wc.y, wc.y, wc.y };
            c = __builtin_amdgcn_mfma_f32_16x16x32_f16(aw, bw, c, 0, 0, 0);
            // C/D: col = lane&15, row = kg*4 + r
            #pragma unroll
            for (int r = 0; r < 4; ++r)
                outp[t][r] = fmaf(fmaxf(c[r], 0.f), wc.x, outp[t][r]);
        }
    }

    // Group-bias constant: folded in exactly once per row via the f==0 blocks.
    if (f == 0) {
        float bs = 0.f;
        #pragma unroll
        for (int i = 0; i < kC; ++i) bs = fmaf(cbias[i], kWCat, bs);
        #pragma unroll
        for (int i = 0; i < kS; ++i) bs = fmaf(sbias[i], kWSub, bs);
        bcon += bs;
    }

    // Reduce over the 16 h2-columns; n==0 lanes add this f's contribution.
    #pragma unroll
    for (int t = 0; t < 4; ++t)
        #pragma unroll
        for (int r = 0; r < 4; ++r) {
            float v = outp[t][r];
            v += __shfl_xor(v, 1);
            v += __shfl_xor(v, 2);
            v += __shfl_xor(v, 4);
            v += __shfl_xor(v, 8);
            if (n == 0)
                atomicAdd(&out[rowbase + t * 16 + kg * 4 + r], v + bcon);
        }
}

extern "C" void kernel_launch(void* const* d_in, const int* in_sizes, int n_in,
                              void* d_out, int out_size, void* d_ws, size_t ws_size,
                              hipStream_t stream) {
    const float* x     = (const float*)d_in[0];
    const float* cW1   = (const float*)d_in[1];
    const float* cB1   = (const float*)d_in[2];
    const float* cW2   = (const float*)d_in[3];
    const float* cB2   = (const float*)d_in[4];
    const float* cW3   = (const float*)d_in[5];
    const float* cB3   = (const float*)d_in[6];
    const float* cbias = (const float*)d_in[7];
    const float* sW1   = (const float*)d_in[8];
    const float* sB1   = (const float*)d_in[9];
    const float* sW2   = (const float*)d_in[10];
    const float* sB2   = (const float*)d_in[11];
    const float* sW3   = (const float*)d_in[12];
    const float* sB3   = (const float*)d_in[13];
    const float* sbias = (const float*)d_in[14];
    float* out = (float*)d_out;
    float* wsPack = (float*)d_ws;     // 960*384 floats = 1.4 MB
    (void)ws_size; (void)n_in; (void)in_sizes; (void)out_size;

    pack_kernel<<<kG * kF, 64, 0, stream>>>(cW1, cB1, cW2, cB2, cW3, cB3,
                                            sW1, sB1, sW2, sB2, sW3, sB3,
                                            wsPack, out);
    nam_packed<<<kF * kChunks, kThreads, 0, stream>>>(x, wsPack, cbias, sbias, out);
}

// Round 11
// 24.232 us; speedup vs baseline: 5.1863x; 1.1080x over previous
//
#include <hip/hip_runtime.h>

typedef __attribute__((ext_vector_type(8))) _Float16 half8;
typedef __attribute__((ext_vector_type(2))) _Float16 half2v;
typedef __attribute__((ext_vector_type(4))) float f32x4;

namespace {
constexpr int kB = 2048;
constexpr int kF = 64;
constexpr int kC = 10;
constexpr int kS = 5;
constexpr int kG = kC + kS;          // 15 groups
constexpr int kH1 = 32;
constexpr int kH2 = 16;
constexpr float kWCat = 0.7f / kC;
constexpr float kWSub = 0.3f / kS;
constexpr int kThreads = 256;        // 4 waves
constexpr int kRowsPerBlock = 128;   // 4 waves x 2 tiles x 16 rows
constexpr int kChunks = kB / kRowsPerBlock;   // 16 -> grid = 64*16 = 1024

// Packed record: 384 floats per (f,g), f-major ([f][g][384]):
//   [0..31]   per kg: [kg*8+0..3]=w1 as half8, [kg*8+4..7]=b1 as half8
//   [32..287] B-fragment: lane l -> half8 at float offset 32+4*l
//   [288..319] {W3[n]*wgt, B2[n]} float pairs at 288+2*n
//   [320]     wgt*b3      [321..383] pad
constexpr int kRecF = 384;
constexpr int kFStageF = kG * kRecF;               // 5760 floats per f
}

// Node 1: pack weights into fragment-ready records (one wave per (g,f);
// every weight byte read from HBM exactly once, coalesced). Blocks 0..31
// additionally zero out[] (nam accumulates into it atomically afterwards).
__global__ __launch_bounds__(64) void pack_kernel(
    const float* __restrict__ cW1, const float* __restrict__ cB1,
    const float* __restrict__ cW2, const float* __restrict__ cB2,
    const float* __restrict__ cW3, const float* __restrict__ cB3,
    const float* __restrict__ sW1, const float* __restrict__ sB1,
    const float* __restrict__ sW2, const float* __restrict__ sB2,
    const float* __restrict__ sW3, const float* __restrict__ sB3,
    float* __restrict__ wsPack, float* __restrict__ out) {
    const int g = blockIdx.x >> 6, f = blockIdx.x & (kF - 1);
    const int l = threadIdx.x;
    if (blockIdx.x < kB / 64) out[blockIdx.x * 64 + l] = 0.f;

    const float *W1, *B1, *W2, *B2, *W3, *B3; float wgt; int base;
    if (g < kC) {
        base = g * kF + f;
        W1 = cW1; B1 = cB1; W2 = cW2; B2 = cB2; W3 = cW3; B3 = cB3; wgt = kWCat;
    } else {
        base = (g - kC) * kF + f;
        W1 = sW1; B1 = sB1; W2 = sW2; B2 = sB2; W3 = sW3; B3 = sB3; wgt = kWSub;
    }
    float* rec = wsPack + ((size_t)f * kG + g) * kRecF;
    unsigned short* rec16 = (unsigned short*)rec;

    // B-fragment: lane l -> fp16(W2[k=(l>>4)*8+j][n=l&15]), j=0..7.
    const int n = l & 15, kg = l >> 4;
    const float* w2p = W2 + (size_t)base * (kH1 * kH2) + (kg * 8) * kH2 + n;
    half8 bw;
    #pragma unroll
    for (int j = 0; j < 8; ++j) bw[j] = (_Float16)w2p[j * kH2];
    *(half8*)(rec + 32 + 4 * l) = bw;

    // w1/b1 as f16: u16 slot kg*16+j (w1) and kg*16+8+j (b1).
    if (l < kH1) {
        const int kgw = l >> 3, j = l & 7;
        rec16[kgw * 16 + j]     = __builtin_bit_cast(unsigned short,
                                      (_Float16)W1[(size_t)base * kH1 + l]);
        rec16[kgw * 16 + 8 + j] = __builtin_bit_cast(unsigned short,
                                      (_Float16)B1[(size_t)base * kH1 + l]);
    }
    if (l < kH2) {
        float2 v;
        v.x = W3[(size_t)base * kH2 + l] * wgt;
        v.y = B2[(size_t)base * kH2 + l];
        *(float2*)(rec + 288 + 2 * l) = v;
    }
    if (l == 0) rec[320] = wgt * B3[base];
}

// Node 2: one block per (f, 128-row chunk): 1024 blocks (4/CU resident).
// Stage this f's 15 packed records (22.5 KB) coalesced, then the packed-f16
// MFMA group loop (2 tiles/wave); atomicAdd per-row contributions into out.
__global__ __launch_bounds__(kThreads, 4) void nam_packed(
    const float* __restrict__ x, const float* __restrict__ wsPack,
    const float* __restrict__ cbias, const float* __restrict__ sbias,
    float* __restrict__ out) {
    const int f     = blockIdx.x & (kF - 1);
    const int chunk = blockIdx.x >> 6;
    const int tid   = threadIdx.x;

    __shared__ float lds[kFStageF];   // 23040 B
    const float4* src = (const float4*)(wsPack + (size_t)f * kFStageF);
    #pragma unroll
    for (int r = 0; r < 6; ++r) {
        const int idx = tid + r * kThreads;
        if (idx < kFStageF / 4) ((float4*)lds)[idx] = src[idx];
    }
    __syncthreads();

    const int wave = tid >> 6;
    const int lane = tid & 63;
    const int n  = lane & 15;
    const int kg = lane >> 4;
    const int rowbase = chunk * kRowsPerBlock + wave * 32;

    // x[row][f]: each 64B line holds 16 f's -> L2-broadcast across blocks.
    half2v xh[2];
    #pragma unroll
    for (int t = 0; t < 2; ++t) {
        const _Float16 v = (_Float16)x[(size_t)(rowbase + t * 16 + n) * kF + f];
        xh[t][0] = v; xh[t][1] = v;
    }

    float outp[2][4] = {{0.f, 0.f, 0.f, 0.f}, {0.f, 0.f, 0.f, 0.f}};
    float bcon = 0.f;
    const half2v hz = { (_Float16)0.f, (_Float16)0.f };

    #pragma unroll 3
    for (int g = 0; g < kG; ++g) {
        const float* rec = lds + g * kRecF;
        const half8 w1h = *(const half8*)(rec + kg * 8);       // w1 j=0..7
        const half8 b1h = *(const half8*)(rec + kg * 8 + 4);   // b1 j=0..7
        const half8 bw  = *(const half8*)(rec + 32 + 4 * lane);
        const float2 wc = *(const float2*)(rec + 288 + 2 * n);
        bcon += rec[320];

        const half2v w01 = { w1h[0], w1h[1] }, w23 = { w1h[2], w1h[3] };
        const half2v w45 = { w1h[4], w1h[5] }, w67 = { w1h[6], w1h[7] };
        const half2v b01 = { b1h[0], b1h[1] }, b23 = { b1h[2], b1h[3] };
        const half2v b45 = { b1h[4], b1h[5] }, b67 = { b1h[6], b1h[7] };

        #pragma unroll
        for (int t = 0; t < 2; ++t) {
            // h1 = relu(x*w1+b1) in packed f16: 4 pk_fma + 4 pk_max.
            half2v p0 = __builtin_elementwise_max(
                __builtin_elementwise_fma(xh[t], w01, b01), hz);
            half2v p1 = __builtin_elementwise_max(
                __builtin_elementwise_fma(xh[t], w23, b23), hz);
            half2v p2 = __builtin_elementwise_max(
                __builtin_elementwise_fma(xh[t], w45, b45), hz);
            half2v p3 = __builtin_elementwise_max(
                __builtin_elementwise_fma(xh[t], w67, b67), hz);
            half8 aw;
            aw[0] = p0[0]; aw[1] = p0[1];
            aw[2] = p1[0]; aw[3] = p1[1];
            aw[4] = p2[0]; aw[5] = p2[1];
            aw[6] = p3[0]; aw[7] = p3[1];
            f32x4 c = { wc.y, wc.y, wc.y, wc.y };
            c = __builtin_amdgcn_mfma_f32_16x16x32_f16(aw, bw, c, 0, 0, 0);
            // C/D: col = lane&15, row = kg*4 + r
            #pragma unroll
            for (int r = 0; r < 4; ++r)
                outp[t][r] = fmaf(fmaxf(c[r], 0.f), wc.x, outp[t][r]);
        }
    }

    // Group-bias constant: folded in exactly once per row via the f==0 blocks.
    if (f == 0) {
        float bs = 0.f;
        #pragma unroll
        for (int i = 0; i < kC; ++i) bs = fmaf(cbias[i], kWCat, bs);
        #pragma unroll
        for (int i = 0; i < kS; ++i) bs = fmaf(sbias[i], kWSub, bs);
        bcon += bs;
    }

    // Reduce over the 16 h2-columns; n==0 lanes add this f's contribution.
    #pragma unroll
    for (int t = 0; t < 2; ++t)
        #pragma unroll
        for (int r = 0; r < 4; ++r) {
            float v = outp[t][r];
            v += __shfl_xor(v, 1);
            v += __shfl_xor(v, 2);
            v += __shfl_xor(v, 4);
            v += __shfl_xor(v, 8);
            if (n == 0)
                atomicAdd(&out[rowbase + t * 16 + kg * 4 + r], v + bcon);
        }
}

extern "C" void kernel_launch(void* const* d_in, const int* in_sizes, int n_in,
                              void* d_out, int out_size, void* d_ws, size_t ws_size,
                              hipStream_t stream) {
    const float* x     = (const float*)d_in[0];
    const float* cW1   = (const float*)d_in[1];
    const float* cB1   = (const float*)d_in[2];
    const float* cW2   = (const float*)d_in[3];
    const float* cB2   = (const float*)d_in[4];
    const float* cW3   = (const float*)d_in[5];
    const float* cB3   = (const float*)d_in[6];
    const float* cbias = (const float*)d_in[7];
    const float* sW1   = (const float*)d_in[8];
    const float* sB1   = (const float*)d_in[9];
    const float* sW2   = (const float*)d_in[10];
    const float* sB2   = (const float*)d_in[11];
    const float* sW3   = (const float*)d_in[12];
    const float* sB3   = (const float*)d_in[13];
    const float* sbias = (const float*)d_in[14];
    float* out = (float*)d_out;
    float* wsPack = (float*)d_ws;     // 960*384 floats = 1.4 MB
    (void)ws_size; (void)n_in; (void)in_sizes; (void)out_size;

    pack_kernel<<<kG * kF, 64, 0, stream>>>(cW1, cB1, cW2, cB2, cW3, cB3,
                                            sW1, sB1, sW2, sB2, sW3, sB3,
                                            wsPack, out);
    nam_packed<<<kF * kChunks, kThreads, 0, stream>>>(x, wsPack, cbias, sbias, out);
}

// Round 12
// 18.315 us; speedup vs baseline: 6.8619x; 1.3231x over previous
//
#include <hip/hip_runtime.h>

typedef __attribute__((ext_vector_type(8))) _Float16 half8;
typedef __attribute__((ext_vector_type(2))) _Float16 half2v;
typedef __attribute__((ext_vector_type(4))) float f32x4;

namespace {
constexpr int kB = 2048;
constexpr int kF = 64;
constexpr int kC = 10;
constexpr int kS = 5;
constexpr int kG = kC + kS;          // 15 groups
constexpr int kH1 = 32;
constexpr int kH2 = 16;
constexpr float kWCat = 0.7f / kC;
constexpr float kWSub = 0.3f / kS;
constexpr int kThreads = 256;        // 4 waves
constexpr int kRowsPerBlock = 128;   // 4 waves x 2 tiles x 16 rows
constexpr int kChunks = kB / kRowsPerBlock;   // 16 -> grid = 64*16 = 1024

// Compact record: 320 floats per (f,g), f-major:
//   [0..31]    w1b1 f16: u16 slot kg*16+j = w1[kg*8+j], kg*16+8+j = b1[kg*8+j]
//   [32..287]  B-fragment (W2^T): lane l -> half8 at float offset 32+4*l
//   [288..319] per kg: [kg*8 +0..3]=b2 quad (f32), [kg*8+4..7]=w3*wgt quad
// Per f: 15 records (4800 floats) + bsum at [4800]; stride 4864 floats.
constexpr int kRecF = 320;
constexpr int kFStride = 4864;
constexpr int kStageF4 = 1201;       // (4800+4)/4 float4s staged
}

// Node 1: pack weights into fragment-ready records (one wave per (g,f)).
// g==0 blocks also compute bsum[f] = sum_g wgt*b3 (+ group-bias at f==0).
// Blocks 0..31 zero out[] (nam accumulates atomically afterwards).
__global__ __launch_bounds__(64) void pack_kernel(
    const float* __restrict__ cW1, const float* __restrict__ cB1,
    const float* __restrict__ cW2, const float* __restrict__ cB2,
    const float* __restrict__ cW3, const float* __restrict__ cB3,
    const float* __restrict__ cbias,
    const float* __restrict__ sW1, const float* __restrict__ sB1,
    const float* __restrict__ sW2, const float* __restrict__ sB2,
    const float* __restrict__ sW3, const float* __restrict__ sB3,
    const float* __restrict__ sbias,
    float* __restrict__ wsPack, float* __restrict__ out) {
    const int g = blockIdx.x >> 6, f = blockIdx.x & (kF - 1);
    const int l = threadIdx.x;
    if (blockIdx.x < kB / 64) out[blockIdx.x * 64 + l] = 0.f;

    const float *W1, *B1, *W2, *B2, *W3, *B3; float wgt; int base;
    if (g < kC) {
        base = g * kF + f;
        W1 = cW1; B1 = cB1; W2 = cW2; B2 = cB2; W3 = cW3; B3 = cB3; wgt = kWCat;
    } else {
        base = (g - kC) * kF + f;
        W1 = sW1; B1 = sB1; W2 = sW2; B2 = sB2; W3 = sW3; B3 = sB3; wgt = kWSub;
    }
    float* rec = wsPack + (size_t)f * kFStride + g * kRecF;
    unsigned short* rec16 = (unsigned short*)rec;

    // B-fragment: lane l -> fp16(W2[k=(l>>4)*8+j][n=l&15]), j=0..7.
    const float* w2p = W2 + (size_t)base * (kH1 * kH2) + ((l >> 4) * 8) * kH2 + (l & 15);
    half8 bw;
    #pragma unroll
    for (int j = 0; j < 8; ++j) bw[j] = (_Float16)w2p[j * kH2];
    *(half8*)(rec + 32 + 4 * l) = bw;

    // w1/b1 as f16.
    if (l < kH1) {
        const int kgw = l >> 3, j = l & 7;
        rec16[kgw * 16 + j]     = __builtin_bit_cast(unsigned short,
                                      (_Float16)W1[(size_t)base * kH1 + l]);
        rec16[kgw * 16 + 8 + j] = __builtin_bit_cast(unsigned short,
                                      (_Float16)B1[(size_t)base * kH1 + l]);
    }
    // b2 / w3*wgt quads, indexed by row n = kg*4 + r.
    if (l < kH2) {
        rec[288 + (l >> 2) * 8 + (l & 3)]     = B2[(size_t)base * kH2 + l];
        rec[288 + (l >> 2) * 8 + 4 + (l & 3)] = W3[(size_t)base * kH2 + l] * wgt;
    }
    // bsum[f]: only the g==0 block computes it.
    if (g == 0) {
        float v = 0.f;
        if (l < kC)            v = kWCat * cB3[l * kF + f];
        else if (l < kG)       v = kWSub * sB3[(l - kC) * kF + f];
        v += __shfl_xor(v, 1);
        v += __shfl_xor(v, 2);
        v += __shfl_xor(v, 4);
        v += __shfl_xor(v, 8);
        if (l == 0) {
            if (f == 0) {
                #pragma unroll
                for (int i = 0; i < kC; ++i) v = fmaf(cbias[i], kWCat, v);
                #pragma unroll
                for (int i = 0; i < kS; ++i) v = fmaf(sbias[i], kWSub, v);
            }
            wsPack[(size_t)f * kFStride + 4800] = v;
        }
    }
}

// Node 2: one block per (f, 128-row chunk): 1024 blocks. Stage this f's 15
// records (19.2 KB) coalesced; transposed-MFMA group loop (2 tiles/wave):
// c = mfma(bw, aw, b2q) puts h2[b][n] at col=b, so the n-reduction is
// per-lane (4 fma) + 2 shfl. One 16-lane atomicAdd row-segment per tile.
__global__ __launch_bounds__(kThreads, 4) void nam_packed(
    const float* __restrict__ x, const float* __restrict__ wsPack,
    float* __restrict__ out) {
    const int f     = blockIdx.x & (kF - 1);
    const int chunk = blockIdx.x >> 6;
    const int tid   = threadIdx.x;

    __shared__ float4 ldsv[kStageF4];   // 19216 B
    const float4* src = (const float4*)(wsPack + (size_t)f * kFStride);
    #pragma unroll
    for (int r = 0; r < 5; ++r) {
        const int idx = tid + r * kThreads;
        if (idx < kStageF4) ldsv[idx] = src[idx];
    }
    __syncthreads();
    const float* lds = (const float*)ldsv;

    const int wave = tid >> 6;
    const int lane = tid & 63;
    const int n  = lane & 15;    // = batch column b in the transposed product
    const int kg = lane >> 4;
    const int rowbase = chunk * kRowsPerBlock + wave * 32;

    half2v xh[2];
    #pragma unroll
    for (int t = 0; t < 2; ++t) {
        const _Float16 v = (_Float16)x[(size_t)(rowbase + t * 16 + n) * kF + f];
        xh[t][0] = v; xh[t][1] = v;
    }

    float acc0 = 0.f, acc1 = 0.f;
    const half2v hz = { (_Float16)0.f, (_Float16)0.f };

    #pragma unroll 3
    for (int g = 0; g < kG; ++g) {
        const float* rec = lds + g * kRecF;
        const half8 w1h = *(const half8*)(rec + kg * 8);       // w1 j=0..7
        const half8 b1h = *(const half8*)(rec + kg * 8 + 4);   // b1 j=0..7
        const half8 bw  = *(const half8*)(rec + 32 + 4 * lane);
        const f32x4 b2q = *(const f32x4*)(rec + 288 + kg * 8);
        const f32x4 w3q = *(const f32x4*)(rec + 288 + kg * 8 + 4);

        const half2v w01 = { w1h[0], w1h[1] }, w23 = { w1h[2], w1h[3] };
        const half2v w45 = { w1h[4], w1h[5] }, w67 = { w1h[6], w1h[7] };
        const half2v b01 = { b1h[0], b1h[1] }, b23 = { b1h[2], b1h[3] };
        const half2v b45 = { b1h[4], b1h[5] }, b67 = { b1h[6], b1h[7] };

        #pragma unroll
        for (int t = 0; t < 2; ++t) {
            half2v p0 = __builtin_elementwise_max(
                __builtin_elementwise_fma(xh[t], w01, b01), hz);
            half2v p1 = __builtin_elementwise_max(
                __builtin_elementwise_fma(xh[t], w23, b23), hz);
            half2v p2 = __builtin_elementwise_max(
                __builtin_elementwise_fma(xh[t], w45, b45), hz);
            half2v p3 = __builtin_elementwise_max(
                __builtin_elementwise_fma(xh[t], w67, b67), hz);
            half8 aw;
            aw[0] = p0[0]; aw[1] = p0[1];
            aw[2] = p1[0]; aw[3] = p1[1];
            aw[4] = p2[0]; aw[5] = p2[1];
            aw[6] = p3[0]; aw[7] = p3[1];
            // Transposed: D = W2^T * h1^T; col = lane&15 = b, row = kg*4+r = n.
            // C-init is the b2 quad straight from LDS.
            f32x4 c = __builtin_amdgcn_mfma_f32_16x16x32_f16(bw, aw, b2q, 0, 0, 0);
            float p = fmaxf(c[0], 0.f) * w3q[0];
            p = fmaf(fmaxf(c[1], 0.f), w3q[1], p);
            p = fmaf(fmaxf(c[2], 0.f), w3q[2], p);
            p = fmaf(fmaxf(c[3], 0.f), w3q[3], p);
            if (t == 0) acc0 += p; else acc1 += p;
        }
    }

    const float bsum = lds[4800];
    #pragma unroll
    for (int t = 0; t < 2; ++t) {
        float v = (t == 0) ? acc0 : acc1;
        v += __shfl_xor(v, 16);
        v += __shfl_xor(v, 32);
        if (lane < 16)
            atomicAdd(&out[rowbase + t * 16 + lane], v + bsum);
    }
}

extern "C" void kernel_launch(void* const* d_in, const int* in_sizes, int n_in,
                              void* d_out, int out_size, void* d_ws, size_t ws_size,
                              hipStream_t stream) {
    const float* x     = (const float*)d_in[0];
    const float* cW1   = (const float*)d_in[1];
    const float* cB1   = (const float*)d_in[2];
    const float* cW2   = (const float*)d_in[3];
    const float* cB2   = (const float*)d_in[4];
    const float* cW3   = (const float*)d_in[5];
    const float* cB3   = (const float*)d_in[6];
    const float* cbias = (const float*)d_in[7];
    const float* sW1   = (const float*)d_in[8];
    const float* sB1   = (const float*)d_in[9];
    const float* sW2   = (const float*)d_in[10];
    const float* sB2   = (const float*)d_in[11];
    const float* sW3   = (const float*)d_in[12];
    const float* sB3   = (const float*)d_in[13];
    const float* sbias = (const float*)d_in[14];
    float* out = (float*)d_out;
    float* wsPack = (float*)d_ws;     // 64*4864 floats = 1.24 MB
    (void)ws_size; (void)n_in; (void)in_sizes; (void)out_size;

    pack_kernel<<<kG * kF, 64, 0, stream>>>(cW1, cB1, cW2, cB2, cW3, cB3, cbias,
                                            sW1, sB1, sW2, sB2, sW3, sB3, sbias,
                                            wsPack, out);
    nam_packed<<<kF * kChunks, kThreads, 0, stream>>>(x, wsPack, out);
}